// Round 4
// baseline (204.792 us; speedup 1.0000x reference)
//
#include <hip/hip_runtime.h>
#include <stdint.h>

typedef float f32x4 __attribute__((ext_vector_type(4)));
typedef __bf16 bf16x8 __attribute__((ext_vector_type(8)));
typedef int i32x2 __attribute__((ext_vector_type(2)));
typedef unsigned short u16;
typedef unsigned int u32;

#define N_NODES 8192
#define F_IN 512
#define F_OUT 128
#define LRA 0.2f
#define JS 8
#define JLEN (N_NODES / JS)
#define CHUNK 128

__device__ __forceinline__ u16 f32_to_bf16(float f) {
  union { float f; u32 u; } v; v.f = f;
  u32 u = v.u;
  u += 0x7fffu + ((u >> 16) & 1u);   // round-to-nearest-even
  return (u16)(u >> 16);
}
__device__ __forceinline__ float dot4(f32x4 a, f32x4 b) {
  return a[0] * b[0] + a[1] * b[1] + a[2] * b[2] + a[3] * b[3];
}

// ---------------------------------------------------------------------------
// prep_k: WT[d][k] = bf16(W[k][d])  (128 x 512), and wa = [W@a1 ; W@a2] fp32.
// ---------------------------------------------------------------------------
__global__ __launch_bounds__(256) void prep_k(
    const float* __restrict__ W, const float* __restrict__ av,
    u16* __restrict__ WT, float* __restrict__ wa) {
  __shared__ u16 Ts[F_OUT][40];
  const int t = threadIdx.x, kc = (int)blockIdx.x * 32;
  {
    const int k = t >> 3, dof = (t & 7) * 16;
#pragma unroll
    for (int q = 0; q < 4; ++q) {
      f32x4 v = *(const f32x4*)&W[(size_t)(kc + k) * F_OUT + dof + q * 4];
#pragma unroll
      for (int e = 0; e < 4; ++e) Ts[dof + q * 4 + e][k] = f32_to_bf16(v[e]);
    }
  }
  __syncthreads();
  {
    const int d = t >> 1, kh = (t & 1) * 16;
    uint4 o0 = *(uint4*)&Ts[d][kh];
    uint4 o1 = *(uint4*)&Ts[d][kh + 8];
    *(uint4*)&WT[(size_t)d * F_IN + kc + kh] = o0;
    *(uint4*)&WT[(size_t)d * F_IN + kc + kh + 8] = o1;
  }
  {
    const int kl = t >> 3, l8 = t & 7;
    const float* wrow = &W[(size_t)(kc + kl) * F_OUT];
    float s1 = 0.f, s2 = 0.f;
#pragma unroll
    for (int q = 0; q < 2; ++q) {
      int dd = l8 * 16 + q * 8;
      f32x4 w0 = *(const f32x4*)&wrow[dd];
      f32x4 w1 = *(const f32x4*)&wrow[dd + 4];
      s1 += dot4(w0, *(const f32x4*)&av[dd]) + dot4(w1, *(const f32x4*)&av[dd + 4]);
      s2 += dot4(w0, *(const f32x4*)&av[F_OUT + dd]) + dot4(w1, *(const f32x4*)&av[F_OUT + dd + 4]);
    }
#pragma unroll
    for (int m = 1; m <= 4; m <<= 1) {
      s1 += __shfl_xor(s1, m, 64);
      s2 += __shfl_xor(s2, m, 64);
    }
    if (l8 == 0) { wa[kc + kl] = s1; wa[F_IN + kc + kl] = s2; }
  }
}

// ---------------------------------------------------------------------------
// gemm_wh: WhT[d][i] = bf16( (h @ W)[i][d] ) via 16x16x32 bf16 MFMA.
// Wh1/Wh2 computed EXACTLY in fp32 as h @ (W@a) fused into A-staging.
// ---------------------------------------------------------------------------
__global__ __launch_bounds__(256) void gemm_wh(
    const float* __restrict__ h, const u16* __restrict__ WT,
    const float* __restrict__ wa,
    u16* __restrict__ WhT, float* __restrict__ Wh1, float* __restrict__ Wh2) {
  __shared__ u16 Ab[2][32][80];
  __shared__ u16 Bs[2][F_OUT][80];
  const int t = threadIdx.x;
  const int i0 = (int)blockIdx.x * 32;
  const int w = t >> 6, l = t & 63, r = l & 15, oct = l >> 4;
  const int mrow = (w & 1) * 16, ncol = (w >> 1) * 64;
  const int ar = t >> 3, ak = (t & 7) * 8;
  const int br = t >> 1, bk = (t & 1) * 32;

  const float* hrow = &h[(size_t)(i0 + ar) * F_IN + ak];
  const u16* wtrow = &WT[(size_t)br * F_IN + bk];
  const float* wap = &wa[ak];
  const float* wbp = &wa[F_IN + ak];

  f32x4 acc[4];
#pragma unroll
  for (int nf = 0; nf < 4; ++nf) acc[nf] = (f32x4){0.f, 0.f, 0.f, 0.f};
  float s1 = 0.f, s2 = 0.f;

  f32x4 ra0, ra1;
  uint4 rb[4];

#define STORE_A(B)                                                        \
  { u32 p0 = f32_to_bf16(ra0[0]) | ((u32)f32_to_bf16(ra0[1]) << 16);      \
    u32 p1 = f32_to_bf16(ra0[2]) | ((u32)f32_to_bf16(ra0[3]) << 16);      \
    u32 p2 = f32_to_bf16(ra1[0]) | ((u32)f32_to_bf16(ra1[1]) << 16);      \
    u32 p3 = f32_to_bf16(ra1[2]) | ((u32)f32_to_bf16(ra1[3]) << 16);      \
    uint4 v; v.x = p0; v.y = p1; v.z = p2; v.w = p3;                      \
    *(uint4*)&Ab[B][ar][ak] = v; }
#define STORE_B(B)                                                        \
  { *(uint4*)&Bs[B][br][bk + 0]  = rb[0];                                 \
    *(uint4*)&Bs[B][br][bk + 8]  = rb[1];                                 \
    *(uint4*)&Bs[B][br][bk + 16] = rb[2];                                 \
    *(uint4*)&Bs[B][br][bk + 24] = rb[3]; }

  ra0 = *(const f32x4*)&hrow[0];
  ra1 = *(const f32x4*)&hrow[4];
#pragma unroll
  for (int j = 0; j < 4; ++j) rb[j] = *(const uint4*)&wtrow[j * 8];
  s1 += dot4(ra0, *(const f32x4*)&wap[0]) + dot4(ra1, *(const f32x4*)&wap[4]);
  s2 += dot4(ra0, *(const f32x4*)&wbp[0]) + dot4(ra1, *(const f32x4*)&wbp[4]);
  STORE_A(0); STORE_B(0);
  __syncthreads();

#pragma unroll
  for (int it = 0; it < 8; ++it) {
    const int buf = it & 1;
    if (it < 7) {
      const int kc = (it + 1) * 64;
      ra0 = *(const f32x4*)&hrow[kc];
      ra1 = *(const f32x4*)&hrow[kc + 4];
#pragma unroll
      for (int j = 0; j < 4; ++j) rb[j] = *(const uint4*)&wtrow[kc + j * 8];
      s1 += dot4(ra0, *(const f32x4*)&wap[kc]) + dot4(ra1, *(const f32x4*)&wap[kc + 4]);
      s2 += dot4(ra0, *(const f32x4*)&wbp[kc]) + dot4(ra1, *(const f32x4*)&wbp[kc + 4]);
    }
#pragma unroll
    for (int ks = 0; ks < 2; ++ks) {
      bf16x8 af = *(bf16x8*)&Ab[buf][mrow + r][ks * 32 + oct * 8];
#pragma unroll
      for (int nf = 0; nf < 4; ++nf) {
        bf16x8 bfv = *(bf16x8*)&Bs[buf][ncol + nf * 16 + r][ks * 32 + oct * 8];
        acc[nf] = __builtin_amdgcn_mfma_f32_16x16x32_bf16(af, bfv, acc[nf], 0, 0, 0);
      }
    }
    if (it < 7) {
      STORE_A(buf ^ 1); STORE_B(buf ^ 1);
      __syncthreads();
    }
  }
#undef STORE_A
#undef STORE_B

#pragma unroll
  for (int m = 1; m <= 4; m <<= 1) {
    s1 += __shfl_xor(s1, m, 64);
    s2 += __shfl_xor(s2, m, 64);
  }
  if ((t & 7) == 0) { Wh1[i0 + ar] = s1; Wh2[i0 + ar] = s2; }

#pragma unroll
  for (int nf = 0; nf < 4; ++nf) {
    u32 lo = f32_to_bf16(acc[nf][0]) | ((u32)f32_to_bf16(acc[nf][1]) << 16);
    u32 hi = f32_to_bf16(acc[nf][2]) | ((u32)f32_to_bf16(acc[nf][3]) << 16);
    const int d = ncol + nf * 16 + r;
    uint2 v; v.x = lo; v.y = hi;
    *(uint2*)&WhT[(size_t)d * N_NODES + i0 + mrow + oct * 4] = v;
  }
}

// ---------------------------------------------------------------------------
// gat_main v3.
// Staging: wave w stages rows w*16..w*16+15; for each row ONE wave-contiguous
// 512B load (64 lanes x int2) -- the 6.3 TB/s pattern. P -> LDS (bf16),
// XOR-swizzled ((row&7)<<4) so MFMA A-frag ds_read_b128 is conflict-free.
// Double-buffered Plds, ONE barrier per 128-col chunk. adj registers
// prefetched one chunk ahead (re-issued as consumed). Denominator summed
// per-lane from the SAME rounded bf16 values -> exact convex combination.
// V-frags direct from L2-resident WhT.
// ---------------------------------------------------------------------------
__device__ __forceinline__ void stage_tile(
    char* plds, const int* abase, const float* w2s, const float* w1s,
    i32x2 (&areg)[16], float (&sden)[16],
    int w, int l, int ch, int chn, bool pref) {
#pragma unroll
  for (int rr = 0; rr < 16; ++rr) {
    i32x2 a2 = areg[rr];
    if (pref)
      areg[rr] = *(const i32x2*)(abase + (size_t)rr * N_NODES + chn + l * 2);
    const int row = w * 16 + rr;
    float cR = w1s[row];
    float xa = cR + w2s[ch + l * 2];
    float xb = cR + w2s[ch + l * 2 + 1];
    xa = fmaxf(xa, LRA * xa);
    xb = fmaxf(xb, LRA * xb);
    float pa = a2[0] ? __expf(xa) : 0.f;
    float pb = a2[1] ? __expf(xb) : 0.f;
    u32 ua = f32_to_bf16(pa), ub = f32_to_bf16(pb);
    union { u32 u; float f; } fa, fb;
    fa.u = ua << 16; fb.u = ub << 16;
    sden[rr] += fa.f + fb.f;               // denom from rounded values
    u32 pk = ua | (ub << 16);
    u32 bo = (u32)(row * (CHUNK * 2) + l * 4) ^ ((u32)(row & 7) << 4);
    *(u32*)(plds + bo) = pk;
  }
}

__global__ __launch_bounds__(256) void gat_main(
    const int* __restrict__ adj, const float* __restrict__ Wh1,
    const float* __restrict__ Wh2, const u16* __restrict__ WhT,
    float* __restrict__ accp, float* __restrict__ sp) {
  __shared__ u16 Plds[2][64][CHUNK];
  __shared__ float w2s[JLEN];
  __shared__ float w1s[64];

  const int t = threadIdx.x;
  const int bi = (int)blockIdx.x / JS;
  const int jsi = (int)blockIdx.x % JS;
  const int i0 = bi * 64;
  const int j0 = jsi * JLEN;
  const int w = t >> 6, l = t & 63, r = l & 15, oct = l >> 4;

  for (int k = t * 4; k < JLEN; k += 1024)
    *(f32x4*)&w2s[k] = *(const f32x4*)&Wh2[j0 + k];
  if (t < 64) w1s[t] = Wh1[i0 + t];
  __syncthreads();

  const int* abase = &adj[(size_t)(i0 + w * 16) * N_NODES + j0];
  const u16* vb0 = &WhT[(size_t)(w * 32 + r) * N_NODES + j0 + oct * 8];
  const u16* vb1 = &WhT[(size_t)(w * 32 + 16 + r) * N_NODES + j0 + oct * 8];

  f32x4 acc[4][2];
#pragma unroll
  for (int it = 0; it < 4; ++it)
#pragma unroll
    for (int dt = 0; dt < 2; ++dt) acc[it][dt] = (f32x4){0.f, 0.f, 0.f, 0.f};
  float sden[16];
#pragma unroll
  for (int rr = 0; rr < 16; ++rr) sden[rr] = 0.f;

  i32x2 areg[16];
#pragma unroll
  for (int rr = 0; rr < 16; ++rr)
    areg[rr] = *(const i32x2*)(abase + (size_t)rr * N_NODES + l * 2);

  int buf = 0;
  for (int ch = 0; ch < JLEN; ch += CHUNK) {
    const bool more = (ch + CHUNK) < JLEN;
    stage_tile((char*)&Plds[buf][0][0], abase, w2s, w1s, areg, sden,
               w, l, ch, ch + CHUNK, more);
    __syncthreads();

#pragma unroll
    for (int ks = 0; ks < 4; ++ks) {
      bf16x8 b0 = *(const bf16x8*)(vb0 + ch + ks * 32);
      bf16x8 b1 = *(const bf16x8*)(vb1 + ch + ks * 32);
      const u32 go = (u32)(((u32)(ks * 4 + oct) ^ (u32)(r & 7)) << 4);
#pragma unroll
      for (int it = 0; it < 4; ++it) {
        u32 ro = (u32)((it * 16 + r) * (CHUNK * 2)) + go;
        bf16x8 af = *(bf16x8*)((char*)&Plds[buf][0][0] + ro);
        acc[it][0] = __builtin_amdgcn_mfma_f32_16x16x32_bf16(af, b0, acc[it][0], 0, 0, 0);
        acc[it][1] = __builtin_amdgcn_mfma_f32_16x16x32_bf16(af, b1, acc[it][1], 0, 0, 0);
      }
    }
    buf ^= 1;
  }

  // ---- denominator: full-wave reduce of each staged row ----
#pragma unroll
  for (int rr = 0; rr < 16; ++rr) {
    float s = sden[rr];
#pragma unroll
    for (int m = 1; m <= 32; m <<= 1) s += __shfl_xor(s, m, 64);
    if (l == rr) sp[(size_t)jsi * N_NODES + i0 + w * 16 + rr] = s;
  }

  // ---- numerator partials: C frag col=lane&15, row=(lane>>4)*4+reg ----
#pragma unroll
  for (int it = 0; it < 4; ++it) {
#pragma unroll
    for (int dt = 0; dt < 2; ++dt) {
#pragma unroll
      for (int rr = 0; rr < 4; ++rr) {
        int row = i0 + it * 16 + oct * 4 + rr;
        int dcol = w * 32 + dt * 16 + r;
        accp[((size_t)jsi * N_NODES + row) * F_OUT + dcol] = acc[it][dt][rr];
      }
    }
  }
}

// ---------------------------------------------------------------------------
// finalize: reduce j-split partials (f32x4 vectorized), divide, ELU.
// ---------------------------------------------------------------------------
__global__ __launch_bounds__(256) void finalize_k(
    const float* __restrict__ accp, const float* __restrict__ sp,
    float* __restrict__ out) {
  const int vidx = (int)blockIdx.x * 256 + threadIdx.x;   // f32x4 index
  const int i = vidx >> 5;                                // node row
  f32x4 num = (f32x4){0.f, 0.f, 0.f, 0.f};
  float den = 0.f;
#pragma unroll
  for (int s = 0; s < JS; ++s) {
    num += *((const f32x4*)accp + (size_t)s * (N_NODES * F_OUT / 4) + vidx);
    den += sp[(size_t)s * N_NODES + i];
  }
  f32x4 o;
#pragma unroll
  for (int c = 0; c < 4; ++c) {
    float x = num[c] / den;
    o[c] = x > 0.f ? x : expm1f(x);
  }
  *((f32x4*)out + vidx) = o;
}

// ---------------------------------------------------------------------------
extern "C" void kernel_launch(void* const* d_in, const int* in_sizes, int n_in,
                              void* d_out, int out_size, void* d_ws, size_t ws_size,
                              hipStream_t stream) {
  const float* h = (const float*)d_in[0];
  const int* adj = (const int*)d_in[1];
  const float* W = (const float*)d_in[2];
  const float* av = (const float*)d_in[3];
  float* out = (float*)d_out;
  char* ws = (char*)d_ws;

  u16* WT = (u16*)ws;                                   // 128 KB
  float* wa = (float*)(ws + (256ull << 10));            // 4 KB
  u16* WhT = (u16*)(ws + (512ull << 10));               // 2 MB
  float* Wh1 = (float*)(ws + (512ull << 10) + (2ull << 20));
  float* Wh2 = (float*)(ws + (512ull << 10) + (2ull << 20) + (32ull << 10));
  float* sp = (float*)(ws + (512ull << 10) + (2ull << 20) + (64ull << 10));
  float* accp = (float*)(ws + (512ull << 10) + (2ull << 20) + (320ull << 10));

  prep_k<<<16, 256, 0, stream>>>(W, av, WT, wa);
  gemm_wh<<<N_NODES / 32, 256, 0, stream>>>(h, WT, wa, WhT, Wh1, Wh2);
  gat_main<<<(N_NODES / 64) * JS, 256, 0, stream>>>(adj, Wh1, Wh2, WhT, accp, sp);
  finalize_k<<<(N_NODES * F_OUT) / 1024, 256, 0, stream>>>(accp, sp, out);
}

// Round 5
// 118.675 us; speedup vs baseline: 1.7257x; 1.7257x over previous
//
#include <hip/hip_runtime.h>
#include <stdint.h>

typedef float f32x4 __attribute__((ext_vector_type(4)));
typedef __bf16 bf16x8 __attribute__((ext_vector_type(8)));
typedef unsigned short u16;
typedef unsigned int u32;

#define N_NODES 8192
#define F_IN 512
#define F_OUT 128
#define LRA 0.2f
#define JS 8
#define JLEN (N_NODES / JS)
#define CHUNK 64
#define NCH (JLEN / CHUNK)
#define I_TILE 32

__device__ __forceinline__ u16 f32_to_bf16(float f) {
  union { float f; u32 u; } v; v.f = f;
  u32 u = v.u;
  u += 0x7fffu + ((u >> 16) & 1u);   // round-to-nearest-even
  return (u16)(u >> 16);
}
__device__ __forceinline__ float dot4(f32x4 a, f32x4 b) {
  return a[0] * b[0] + a[1] * b[1] + a[2] * b[2] + a[3] * b[3];
}

// ---------------------------------------------------------------------------
// prep_k: WT[d][k] = bf16(W[k][d])  (128 x 512), and wa = [W@a1 ; W@a2] fp32.
// ---------------------------------------------------------------------------
__global__ __launch_bounds__(256) void prep_k(
    const float* __restrict__ W, const float* __restrict__ av,
    u16* __restrict__ WT, float* __restrict__ wa) {
  __shared__ u16 Ts[F_OUT][40];
  const int t = threadIdx.x, kc = (int)blockIdx.x * 32;
  {
    const int k = t >> 3, dof = (t & 7) * 16;
#pragma unroll
    for (int q = 0; q < 4; ++q) {
      f32x4 v = *(const f32x4*)&W[(size_t)(kc + k) * F_OUT + dof + q * 4];
#pragma unroll
      for (int e = 0; e < 4; ++e) Ts[dof + q * 4 + e][k] = f32_to_bf16(v[e]);
    }
  }
  __syncthreads();
  {
    const int d = t >> 1, kh = (t & 1) * 16;
    uint4 o0 = *(uint4*)&Ts[d][kh];
    uint4 o1 = *(uint4*)&Ts[d][kh + 8];
    *(uint4*)&WT[(size_t)d * F_IN + kc + kh] = o0;
    *(uint4*)&WT[(size_t)d * F_IN + kc + kh + 8] = o1;
  }
  {
    const int kl = t >> 3, l8 = t & 7;
    const float* wrow = &W[(size_t)(kc + kl) * F_OUT];
    float s1 = 0.f, s2 = 0.f;
#pragma unroll
    for (int q = 0; q < 2; ++q) {
      int dd = l8 * 16 + q * 8;
      f32x4 w0 = *(const f32x4*)&wrow[dd];
      f32x4 w1 = *(const f32x4*)&wrow[dd + 4];
      s1 += dot4(w0, *(const f32x4*)&av[dd]) + dot4(w1, *(const f32x4*)&av[dd + 4]);
      s2 += dot4(w0, *(const f32x4*)&av[F_OUT + dd]) + dot4(w1, *(const f32x4*)&av[F_OUT + dd + 4]);
    }
#pragma unroll
    for (int m = 1; m <= 4; m <<= 1) {
      s1 += __shfl_xor(s1, m, 64);
      s2 += __shfl_xor(s2, m, 64);
    }
    if (l8 == 0) { wa[kc + kl] = s1; wa[F_IN + kc + kl] = s2; }
  }
}

// ---------------------------------------------------------------------------
// gemm_wh: WhT[d][i] = bf16( (h @ W)[i][d] ) via 16x16x32 bf16 MFMA.
// Wh1/Wh2 computed EXACTLY in fp32 as h @ (W@a) fused into A-staging.
// ---------------------------------------------------------------------------
__global__ __launch_bounds__(256) void gemm_wh(
    const float* __restrict__ h, const u16* __restrict__ WT,
    const float* __restrict__ wa,
    u16* __restrict__ WhT, float* __restrict__ Wh1, float* __restrict__ Wh2) {
  __shared__ u16 Ab[2][32][80];
  __shared__ u16 Bs[2][F_OUT][80];
  const int t = threadIdx.x;
  const int i0 = (int)blockIdx.x * 32;
  const int w = t >> 6, l = t & 63, r = l & 15, oct = l >> 4;
  const int mrow = (w & 1) * 16, ncol = (w >> 1) * 64;
  const int ar = t >> 3, ak = (t & 7) * 8;
  const int br = t >> 1, bk = (t & 1) * 32;

  const float* hrow = &h[(size_t)(i0 + ar) * F_IN + ak];
  const u16* wtrow = &WT[(size_t)br * F_IN + bk];
  const float* wap = &wa[ak];
  const float* wbp = &wa[F_IN + ak];

  f32x4 acc[4];
#pragma unroll
  for (int nf = 0; nf < 4; ++nf) acc[nf] = (f32x4){0.f, 0.f, 0.f, 0.f};
  float s1 = 0.f, s2 = 0.f;

  f32x4 ra0, ra1;
  uint4 rb[4];

#define STORE_A(B)                                                        \
  { u32 p0 = f32_to_bf16(ra0[0]) | ((u32)f32_to_bf16(ra0[1]) << 16);      \
    u32 p1 = f32_to_bf16(ra0[2]) | ((u32)f32_to_bf16(ra0[3]) << 16);      \
    u32 p2 = f32_to_bf16(ra1[0]) | ((u32)f32_to_bf16(ra1[1]) << 16);      \
    u32 p3 = f32_to_bf16(ra1[2]) | ((u32)f32_to_bf16(ra1[3]) << 16);      \
    uint4 v; v.x = p0; v.y = p1; v.z = p2; v.w = p3;                      \
    *(uint4*)&Ab[B][ar][ak] = v; }
#define STORE_B(B)                                                        \
  { *(uint4*)&Bs[B][br][bk + 0]  = rb[0];                                 \
    *(uint4*)&Bs[B][br][bk + 8]  = rb[1];                                 \
    *(uint4*)&Bs[B][br][bk + 16] = rb[2];                                 \
    *(uint4*)&Bs[B][br][bk + 24] = rb[3]; }

  ra0 = *(const f32x4*)&hrow[0];
  ra1 = *(const f32x4*)&hrow[4];
#pragma unroll
  for (int j = 0; j < 4; ++j) rb[j] = *(const uint4*)&wtrow[j * 8];
  s1 += dot4(ra0, *(const f32x4*)&wap[0]) + dot4(ra1, *(const f32x4*)&wap[4]);
  s2 += dot4(ra0, *(const f32x4*)&wbp[0]) + dot4(ra1, *(const f32x4*)&wbp[4]);
  STORE_A(0); STORE_B(0);
  __syncthreads();

#pragma unroll
  for (int it = 0; it < 8; ++it) {
    const int buf = it & 1;
    if (it < 7) {
      const int kc = (it + 1) * 64;
      ra0 = *(const f32x4*)&hrow[kc];
      ra1 = *(const f32x4*)&hrow[kc + 4];
#pragma unroll
      for (int j = 0; j < 4; ++j) rb[j] = *(const uint4*)&wtrow[kc + j * 8];
      s1 += dot4(ra0, *(const f32x4*)&wap[kc]) + dot4(ra1, *(const f32x4*)&wap[kc + 4]);
      s2 += dot4(ra0, *(const f32x4*)&wbp[kc]) + dot4(ra1, *(const f32x4*)&wbp[kc + 4]);
    }
#pragma unroll
    for (int ks = 0; ks < 2; ++ks) {
      bf16x8 af = *(bf16x8*)&Ab[buf][mrow + r][ks * 32 + oct * 8];
#pragma unroll
      for (int nf = 0; nf < 4; ++nf) {
        bf16x8 bfv = *(bf16x8*)&Bs[buf][ncol + nf * 16 + r][ks * 32 + oct * 8];
        acc[nf] = __builtin_amdgcn_mfma_f32_16x16x32_bf16(af, bfv, acc[nf], 0, 0, 0);
      }
    }
    if (it < 7) {
      STORE_A(buf ^ 1); STORE_B(buf ^ 1);
      __syncthreads();
    }
  }
#undef STORE_A
#undef STORE_B

#pragma unroll
  for (int m = 1; m <= 4; m <<= 1) {
    s1 += __shfl_xor(s1, m, 64);
    s2 += __shfl_xor(s2, m, 64);
  }
  if ((t & 7) == 0) { Wh1[i0 + ar] = s1; Wh2[i0 + ar] = s2; }

#pragma unroll
  for (int nf = 0; nf < 4; ++nf) {
    u32 lo = f32_to_bf16(acc[nf][0]) | ((u32)f32_to_bf16(acc[nf][1]) << 16);
    u32 hi = f32_to_bf16(acc[nf][2]) | ((u32)f32_to_bf16(acc[nf][3]) << 16);
    const int d = ncol + nf * 16 + r;
    uint2 v; v.x = lo; v.y = hi;
    *(uint2*)&WhT[(size_t)d * N_NODES + i0 + mrow + oct * 4] = v;
  }
}

// ---------------------------------------------------------------------------
// gat_main v4: 32-row i-tile, CHUNK=64, 2-deep named-register pipeline.
// Staging: thread t owns row (t>>3), cols (t&7)*8..+7 -> per wave-instr the
// 64 lanes read 8 FULL 128B cache lines. P tile XOR-swizzled ((row&7)<<4):
// b128 writes AND A-frag reads conflict-free. adj(ch+2) / V(ch+1) issued at
// body top (right after the barrier) so the pre-barrier vmcnt drain comes
// ~600cy after issue. One barrier per chunk. LDS 12.3KB -> 8 blocks/CU.
// Denominator summed from the SAME rounded bf16 P values (exact convex comb).
// ---------------------------------------------------------------------------
__global__ __launch_bounds__(256) void gat_main(
    const int* __restrict__ adj, const float* __restrict__ Wh1,
    const float* __restrict__ Wh2, const u16* __restrict__ WhT,
    float* __restrict__ accp, float* __restrict__ sp) {
  __shared__ __align__(16) u16 Plds[2][I_TILE * CHUNK];
  __shared__ float w2s[JLEN];

  const int t = threadIdx.x;
  const int bi = (int)blockIdx.x / JS;
  const int jsi = (int)blockIdx.x % JS;
  const int i0 = bi * I_TILE;
  const int j0 = jsi * JLEN;
  const int w = t >> 6, l = t & 63, r = l & 15, oct = l >> 4;
  const int il = t >> 3, cg = t & 7;

  for (int k = t * 4; k < JLEN; k += 1024)
    *(f32x4*)&w2s[k] = *(const f32x4*)&Wh2[j0 + k];

  const float cI = Wh1[i0 + il];
  const int* aptr = &adj[(size_t)(i0 + il) * N_NODES + j0 + cg * 8];
  const u32 wb = (u32)(il * (CHUNK * 2)) + (((u32)cg * 16) ^ (((u32)il & 7) << 4));

  const u16* vpt0 = &WhT[(size_t)(w * 32 + r) * N_NODES + j0 + oct * 8];
  const u16* vpt1 = &WhT[(size_t)(w * 32 + 16 + r) * N_NODES + j0 + oct * 8];

  f32x4 acc[2][2];
#pragma unroll
  for (int it = 0; it < 2; ++it)
#pragma unroll
    for (int dt = 0; dt < 2; ++dt) acc[it][dt] = (f32x4){0.f, 0.f, 0.f, 0.f};
  float sden = 0.f;

#define STAGE(a0, a1, CH, B) do {                                           \
    f32x4 wv0 = *(const f32x4*)&w2s[(CH) * CHUNK + cg * 8];                 \
    f32x4 wv1 = *(const f32x4*)&w2s[(CH) * CHUNK + cg * 8 + 4];             \
    u32 pk[4];                                                              \
    _Pragma("unroll")                                                       \
    for (int q = 0; q < 4; ++q) {                                           \
      int aa = (q == 0) ? a0.x : (q == 1) ? a0.z : (q == 2) ? a1.x : a1.z;  \
      int ab = (q == 0) ? a0.y : (q == 1) ? a0.w : (q == 2) ? a1.y : a1.w;  \
      float wA = (q < 2) ? wv0[q * 2] : wv1[(q - 2) * 2];                   \
      float wB = (q < 2) ? wv0[q * 2 + 1] : wv1[(q - 2) * 2 + 1];           \
      float xA = cI + wA; xA = fmaxf(xA, LRA * xA);                         \
      float xB = cI + wB; xB = fmaxf(xB, LRA * xB);                         \
      float pA = aa ? __expf(xA) : 0.f;                                     \
      float pB = ab ? __expf(xB) : 0.f;                                     \
      u32 uA = f32_to_bf16(pA), uB = f32_to_bf16(pB);                       \
      union { u32 u; float f; } fA, fB; fA.u = uA << 16; fB.u = uB << 16;   \
      sden += fA.f + fB.f;                                                  \
      pk[q] = uA | (uB << 16);                                              \
    }                                                                       \
    uint4 pv; pv.x = pk[0]; pv.y = pk[1]; pv.z = pk[2]; pv.w = pk[3];       \
    *(uint4*)((char*)&Plds[B][0] + wb) = pv;                                \
  } while (0)

#define MMA(B, V) do {                                                     \
    _Pragma("unroll")                                                      \
    for (int ks = 0; ks < 2; ++ks) {                                       \
      _Pragma("unroll")                                                    \
      for (int it = 0; it < 2; ++it) {                                     \
        u32 rb_ = (u32)((it * 16 + r) * (CHUNK * 2))                       \
                + (((u32)(oct * 16 + ks * 64)) ^ (((u32)r & 7) << 4));     \
        bf16x8 af = *(bf16x8*)((char*)&Plds[B][0] + rb_);                  \
        acc[it][0] = __builtin_amdgcn_mfma_f32_16x16x32_bf16(af, V[ks], acc[it][0], 0, 0, 0);     \
        acc[it][1] = __builtin_amdgcn_mfma_f32_16x16x32_bf16(af, V[2 + ks], acc[it][1], 0, 0, 0); \
      }                                                                    \
    }                                                                      \
  } while (0)

  int4 aE0, aE1, aO0, aO1;
  bf16x8 vc[4], vn[4];

  // ---- prologue: adj(0)->E, adj(1)->O, V(0)->vc, stage chunk0 -> P[0] ----
  aE0 = *(const int4*)(aptr + 0);
  aE1 = *(const int4*)(aptr + 4);
  aO0 = *(const int4*)(aptr + CHUNK);
  aO1 = *(const int4*)(aptr + CHUNK + 4);
  vc[0] = *(const bf16x8*)(vpt0 + 0);
  vc[1] = *(const bf16x8*)(vpt0 + 32);
  vc[2] = *(const bf16x8*)(vpt1 + 0);
  vc[3] = *(const bf16x8*)(vpt1 + 32);
  __syncthreads();                 // w2s ready
  STAGE(aE0, aE1, 0, 0);
  __syncthreads();                 // P[0] ready

#pragma unroll 1
  for (int ch = 0; ch < NCH; ch += 2) {
    // ---- body A: compute chunk ch (P[0], vc); stage ch+1 -> P[1] ----
    if (ch + 2 < NCH) {
      aE0 = *(const int4*)(aptr + (ch + 2) * CHUNK);
      aE1 = *(const int4*)(aptr + (ch + 2) * CHUNK + 4);
    }
    vn[0] = *(const bf16x8*)(vpt0 + (ch + 1) * CHUNK);
    vn[1] = *(const bf16x8*)(vpt0 + (ch + 1) * CHUNK + 32);
    vn[2] = *(const bf16x8*)(vpt1 + (ch + 1) * CHUNK);
    vn[3] = *(const bf16x8*)(vpt1 + (ch + 1) * CHUNK + 32);
    MMA(0, vc);
    STAGE(aO0, aO1, ch + 1, 1);
    __syncthreads();

    // ---- body B: compute chunk ch+1 (P[1], vn); stage ch+2 -> P[0] ----
    if (ch + 3 < NCH) {
      aO0 = *(const int4*)(aptr + (ch + 3) * CHUNK);
      aO1 = *(const int4*)(aptr + (ch + 3) * CHUNK + 4);
    }
    if (ch + 2 < NCH) {
      vc[0] = *(const bf16x8*)(vpt0 + (ch + 2) * CHUNK);
      vc[1] = *(const bf16x8*)(vpt0 + (ch + 2) * CHUNK + 32);
      vc[2] = *(const bf16x8*)(vpt1 + (ch + 2) * CHUNK);
      vc[3] = *(const bf16x8*)(vpt1 + (ch + 2) * CHUNK + 32);
    }
    MMA(1, vn);
    if (ch + 2 < NCH) {
      STAGE(aE0, aE1, ch + 2, 0);
      __syncthreads();
    }
  }
#undef STAGE
#undef MMA

  // ---- denominator: reduce the 8 lanes sharing row il ----
  {
    float s = sden;
    s += __shfl_xor(s, 1, 64);
    s += __shfl_xor(s, 2, 64);
    s += __shfl_xor(s, 4, 64);
    if ((l & 7) == 0) sp[(size_t)jsi * N_NODES + i0 + il] = s;
  }

  // ---- numerator partials: C frag col=lane&15, row=(lane>>4)*4+reg ----
  float* ap = &accp[((size_t)jsi * N_NODES + i0 + oct * 4) * F_OUT + w * 32 + r];
#pragma unroll
  for (int it = 0; it < 2; ++it)
#pragma unroll
    for (int dt = 0; dt < 2; ++dt)
#pragma unroll
      for (int rr = 0; rr < 4; ++rr)
        ap[(size_t)(it * 16 + rr) * F_OUT + dt * 16] = acc[it][dt][rr];
}

// ---------------------------------------------------------------------------
// finalize: reduce j-split partials (f32x4 vectorized), divide, ELU.
// ---------------------------------------------------------------------------
__global__ __launch_bounds__(256) void finalize_k(
    const float* __restrict__ accp, const float* __restrict__ sp,
    float* __restrict__ out) {
  const int vidx = (int)blockIdx.x * 256 + threadIdx.x;   // f32x4 index
  const int i = vidx >> 5;                                // node row
  f32x4 num = (f32x4){0.f, 0.f, 0.f, 0.f};
  float den = 0.f;
#pragma unroll
  for (int s = 0; s < JS; ++s) {
    num += *((const f32x4*)accp + (size_t)s * (N_NODES * F_OUT / 4) + vidx);
    den += sp[(size_t)s * N_NODES + i];
  }
  f32x4 o;
#pragma unroll
  for (int c = 0; c < 4; ++c) {
    float x = num[c] / den;
    o[c] = x > 0.f ? x : expm1f(x);
  }
  *((f32x4*)out + vidx) = o;
}

// ---------------------------------------------------------------------------
extern "C" void kernel_launch(void* const* d_in, const int* in_sizes, int n_in,
                              void* d_out, int out_size, void* d_ws, size_t ws_size,
                              hipStream_t stream) {
  const float* h = (const float*)d_in[0];
  const int* adj = (const int*)d_in[1];
  const float* W = (const float*)d_in[2];
  const float* av = (const float*)d_in[3];
  float* out = (float*)d_out;
  char* ws = (char*)d_ws;

  u16* WT = (u16*)ws;                                   // 128 KB
  float* wa = (float*)(ws + (256ull << 10));            // 4 KB
  u16* WhT = (u16*)(ws + (512ull << 10));               // 2 MB
  float* Wh1 = (float*)(ws + (512ull << 10) + (2ull << 20));
  float* Wh2 = (float*)(ws + (512ull << 10) + (2ull << 20) + (32ull << 10));
  float* sp = (float*)(ws + (512ull << 10) + (2ull << 20) + (64ull << 10));
  float* accp = (float*)(ws + (512ull << 10) + (2ull << 20) + (320ull << 10));

  prep_k<<<16, 256, 0, stream>>>(W, av, WT, wa);
  gemm_wh<<<N_NODES / 32, 256, 0, stream>>>(h, WT, wa, WhT, Wh1, Wh2);
  gat_main<<<(N_NODES / I_TILE) * JS, 256, 0, stream>>>(adj, Wh1, Wh2, WhT, accp, sp);
  finalize_k<<<(N_NODES * F_OUT) / 1024, 256, 0, stream>>>(accp, sp, out);
}